// Round 9
// baseline (406.029 us; speedup 1.0000x reference)
//
#include <hip/hip_runtime.h>
#include <hip/hip_bf16.h>
#include <math.h>

#define IN_CH 512
#define MID_CH 64
#define OUT_CH 40

typedef __attribute__((ext_vector_type(8))) short short8;
typedef __attribute__((ext_vector_type(4))) float f32x4;
typedef __attribute__((ext_vector_type(2))) float f32x2;

static __device__ __forceinline__ unsigned short f2bf(float f) {
    unsigned int u = __float_as_uint(f);
    u += 0x7fffu + ((u >> 16) & 1u);   // round-to-nearest-even on bf16 boundary
    return (unsigned short)(u >> 16);
}

// ---------------- degree count (simple; cnt is 400KB -> L2-friendly) --------------
__global__ void k_count(const int* __restrict__ dst, int* __restrict__ cnt, int E) {
    int i = blockIdx.x * blockDim.x + threadIdx.x;
    if (i < E) atomicAdd(&cnt[dst[i]], 1);
}

// ---------------- CSR scan over PADDED degrees (round up to 8); dis from real deg --
__global__ void k_scanA(const int* __restrict__ cnt, int* __restrict__ rowptr,
                        int* __restrict__ bsum, float* __restrict__ dis, int N) {
    __shared__ int wsum[16];
    int i = blockIdx.x * 1024 + threadIdx.x;
    int lane = threadIdx.x & 63, wv = threadIdx.x >> 6;
    int v = (i < N) ? cnt[i] : 0;
    if (i < N) dis[i] = rsqrtf((float)v + 1.0f);
    int x = (v + 7) & ~7;                      // padded degree (mult of 8)
    #pragma unroll
    for (int off = 1; off < 64; off <<= 1) {
        int t = __shfl_up(x, off);
        if (lane >= off) x += t;
    }
    if (lane == 63) wsum[wv] = x;
    __syncthreads();
    if (wv == 0 && lane < 16) {
        int own = wsum[lane];
        int y = own;
        #pragma unroll
        for (int off = 1; off < 16; off <<= 1) {
            int t = __shfl_up(y, off);
            if (lane >= off) y += t;
        }
        wsum[lane] = y - own;
        if (lane == 15) bsum[blockIdx.x] = y;
    }
    __syncthreads();
    if (i < N) rowptr[i + 1] = x + wsum[wv];
}

__global__ void k_scanB(int* __restrict__ bsum, int nb) {
    __shared__ int tmp[2];
    int lane = threadIdx.x & 63, wv = threadIdx.x >> 6;
    int v = (threadIdx.x < nb) ? bsum[threadIdx.x] : 0;
    int x = v;
    #pragma unroll
    for (int off = 1; off < 64; off <<= 1) {
        int t = __shfl_up(x, off);
        if (lane >= off) x += t;
    }
    if (lane == 63) tmp[wv] = x;
    __syncthreads();
    int add = (wv == 1) ? tmp[0] : 0;
    if (threadIdx.x < nb) bsum[threadIdx.x] = x - v + add;
}

// C: add chunk offsets; ALSO initialize cursor cur[] = rowptr[]
__global__ void k_scanC(int* __restrict__ rowptr, int* __restrict__ cur,
                        const int* __restrict__ bsum, int N) {
    int i = blockIdx.x * 1024 + threadIdx.x;
    if (i < N) {
        int v = rowptr[i + 1] + bsum[blockIdx.x];
        rowptr[i + 1] = v;
        cur[i + 1] = v;
    }
    if (i == 0) { rowptr[0] = 0; cur[0] = 0; }
}

// ---------------- init padded esrc slots to dummy-row byte offset ----------------
__global__ void k_padfill(int* __restrict__ esrc, int dummy_off, int total) {
    int i = blockIdx.x * blockDim.x + threadIdx.x;
    if (i < total) esrc[i] = dummy_off;
}

// ---------------- fill CSR (partitioned by dst&7 for esrc write locality) ---------
__global__ void k_fill(const int* __restrict__ src, const int* __restrict__ dst,
                       int* __restrict__ cur, int* __restrict__ esrc, int E) {
    int pb = blockIdx.x & 7;
    int ch = blockIdx.x >> 3;
    int nch = gridDim.x >> 3;
    int ech = (E + nch - 1) / nch;
    int e0 = ch * ech;
    int e1 = e0 + ech; if (e1 > E) e1 = E;
    #pragma unroll 4
    for (int e = e0 + (int)threadIdx.x; e < e1; e += blockDim.x) {
        int d = dst[e];
        if ((d & 7) == pb) {
            int p = atomicAdd(&cur[d], 1);
            esrc[p] = src[e] << 5;      // byte offset of 32-B half-table row
        }
    }
}

// ---------------- prep W1: fp32 [512][64] -> bf16 fragment layout -----------------
__global__ void k_prepw(const float* __restrict__ W1, unsigned short* __restrict__ w1f) {
    int f = blockIdx.x * 256 + threadIdx.x;      // 32768 total
    int k = f >> 6, c = f & 63;
    w1f[(((k >> 3) * 64) + c) * 8 + (k & 7)] = f2bf(W1[f]);
}

// ---------------- GEMM1: {h1A,h1B} = fp8(dis[row] * (X @ W1)), split halves -------
// 256 thr = 4 waves; block = 64 rows x 64 cols; no LDS (w1f L1/L2-resident).
__launch_bounds__(256, 6)
__global__ void k_gemm1(const float* __restrict__ X, const unsigned short* __restrict__ w1f,
                        const float* __restrict__ dis,
                        unsigned char* __restrict__ h1A, unsigned char* __restrict__ h1B,
                        int N) {
    int wave = threadIdx.x >> 6, lane = threadIdx.x & 63;
    int rbase = blockIdx.x * 64 + wave * 16;
    int g = lane >> 4;
    int arow = rbase + (lane & 15);
    if (arow > N - 1) arow = N - 1;              // clamp loads; stores are guarded
    const float* xp = X + (size_t)arow * IN_CH + g * 8;
    const short8* wb = (const short8*)w1f;

    f32x4 acc[4];
    #pragma unroll
    for (int i = 0; i < 4; ++i) acc[i] = (f32x4){0.f, 0.f, 0.f, 0.f};

    float4 bx0[2], bx1[2];
    {
        const float4* p0 = (const float4*)(xp);
        const float4* p1 = (const float4*)(xp + 32);
        bx0[0] = p0[0]; bx1[0] = p0[1];
        bx0[1] = p1[0]; bx1[1] = p1[1];
    }

    #pragma unroll
    for (int ks = 0; ks < 16; ++ks) {
        float4 x0 = bx0[ks & 1], x1 = bx1[ks & 1];
        if (ks < 14) {
            const float4* p = (const float4*)(xp + (ks + 2) * 32);
            bx0[ks & 1] = p[0]; bx1[ks & 1] = p[1];
        }
        short8 a;
        a[0] = (short)f2bf(x0.x); a[1] = (short)f2bf(x0.y);
        a[2] = (short)f2bf(x0.z); a[3] = (short)f2bf(x0.w);
        a[4] = (short)f2bf(x1.x); a[5] = (short)f2bf(x1.y);
        a[6] = (short)f2bf(x1.z); a[7] = (short)f2bf(x1.w);

        int cibase = (ks * 4 + g) * 64 + (lane & 15);
        #pragma unroll
        for (int ct = 0; ct < 4; ++ct) {
            short8 b = wb[cibase + ct * 16];
            acc[ct] = __builtin_amdgcn_mfma_f32_16x16x32_bf16(a, b, acc[ct], 0, 0, 0);
        }
    }

    // D layout: col = lane&15, row = (lane>>4)*4 + reg ; ct0,1 -> half A, ct2,3 -> B
    int colb = lane & 15;
    int rquad = rbase + (lane >> 4) * 4;
    #pragma unroll
    for (int ct = 0; ct < 4; ++ct) {
        unsigned char* tbl = (ct < 2) ? h1A : h1B;
        int coloff = (ct & 1) * 16 + colb;
        #pragma unroll
        for (int r = 0; r < 4; ++r) {
            int row = rquad + r;
            if (row < N) {
                float v = acc[ct][r] * dis[row];
                unsigned q = __builtin_amdgcn_cvt_pk_fp8_f32(v, v, 0, false);
                tbl[(size_t)row * 32 + coloff] = (unsigned char)q;
            }
        }
    }
}

// ---- fp8 gather unpack: one u32 = 4 channels ----
#define AGG_UNPACK8(Q)                                              \
    {                                                               \
        f32x2 lo_ = __builtin_amdgcn_cvt_pk_f32_fp8((Q), false);    \
        f32x2 hi_ = __builtin_amdgcn_cvt_pk_f32_fp8((Q), true);     \
        acc[0] += lo_[0]; acc[1] += lo_[1];                         \
        acc[2] += hi_[0]; acc[3] += hi_[1];                         \
    }

// ---- shared gather core: 32-B rows, 8 edge-subgroups x 8 channel-lanes ----
// returns per-lane partial acc (g-subgroup reduced at caller)
#define GATHER_CORE(HB)                                                 \
    f32x4 acc = (f32x4){0.f, 0.f, 0.f, 0.f};                            \
    for (int cbeg = beg; cbeg < end; cbeg += 64) {                      \
        int m = end - cbeg; if (m > 64) m = 64;  /* multiple of 8 */    \
        int soff = esrc[cbeg + lane];                                   \
        int k8n = m >> 3;                                               \
        int k8 = 0;                                                     \
        for (; k8 + 2 <= k8n; k8 += 2) {                                \
            int o0 = __shfl(soff, (k8 + 0) * 8 + g);                    \
            int o1 = __shfl(soff, (k8 + 1) * 8 + g);                    \
            unsigned q0 = *(const unsigned*)((HB) + ((unsigned)o0 + cgoff)); \
            unsigned q1 = *(const unsigned*)((HB) + ((unsigned)o1 + cgoff)); \
            AGG_UNPACK8(q0) AGG_UNPACK8(q1)                             \
        }                                                               \
        for (; k8 < k8n; ++k8) {                                        \
            int o = __shfl(soff, k8 * 8 + g);                           \
            unsigned q = *(const unsigned*)((HB) + ((unsigned)o + cgoff)); \
            AGG_UNPACK8(q)                                              \
        }                                                               \
    }                                                                   \
    _Pragma("unroll")                                                   \
    for (int off = 32; off >= 8; off >>= 1) {                           \
        acc[0] += __shfl_xor(acc[0], off);                              \
        acc[1] += __shfl_xor(acc[1], off);                              \
        acc[2] += __shfl_xor(acc[2], off);                              \
        acc[3] += __shfl_xor(acc[3], off);                              \
    }

// ---------------- layer 1 (one half): gather + finish + elu -----------------------
__launch_bounds__(256)
__global__ void k_agg1(const unsigned char* __restrict__ hq, const float* __restrict__ dis,
                       const int* __restrict__ rowptr, const int* __restrict__ esrc,
                       const float* __restrict__ bias, unsigned char* __restrict__ hdst,
                       int N) {
    int wv = threadIdx.x >> 6, lane = threadIdx.x & 63;
    int n = blockIdx.x * 4 + wv;
    if (n >= N) return;
    int g = lane >> 3, cg = lane & 7;
    int beg = rowptr[n], end = rowptr[n + 1];
    unsigned cgoff = (unsigned)(cg * 4);
    const char* hb = (const char*)hq;

    GATHER_CORE(hb)

    if (g == 0) {
        float dn = dis[n];
        unsigned qs = *(const unsigned*)(hb + ((unsigned)(n * 32) + cgoff));
        f32x2 slo = __builtin_amdgcn_cvt_pk_f32_fp8(qs, false);
        f32x2 shi = __builtin_amdgcn_cvt_pk_f32_fp8(qs, true);
        float4 b4 = *(const float4*)(bias + cg * 4);
        float v0 = dn * (acc[0] + slo[0]) + b4.x;
        float v1 = dn * (acc[1] + slo[1]) + b4.y;
        float v2 = dn * (acc[2] + shi[0]) + b4.z;
        float v3 = dn * (acc[3] + shi[1]) + b4.w;
        v0 = v0 > 0.f ? v0 : expm1f(v0);
        v1 = v1 > 0.f ? v1 : expm1f(v1);
        v2 = v2 > 0.f ? v2 : expm1f(v2);
        v3 = v3 > 0.f ? v3 : expm1f(v3);
        unsigned w = __builtin_amdgcn_cvt_pk_fp8_f32(dn * v0, dn * v1, 0, false);
        w = __builtin_amdgcn_cvt_pk_fp8_f32(dn * v2, dn * v3, w, true);
        *(unsigned*)(hdst + (size_t)n * 32 + cg * 4) = w;
    }
}

// ---------------- layer 2 (one half): gather + partial GEMM2 (+ softmax on final) --
__launch_bounds__(256)
__global__ void k_agg2(const unsigned char* __restrict__ hq, const float* __restrict__ dis,
                       const int* __restrict__ rowptr, const int* __restrict__ esrc,
                       const float* __restrict__ W2half, const float* __restrict__ b2,
                       float* __restrict__ opart, float* __restrict__ out,
                       int N, int final_pass) {
    __shared__ float w2l[32 * OUT_CH + 64];
    __shared__ float vl[4 * 32];
    for (int f = threadIdx.x; f < 32 * OUT_CH; f += 256) w2l[f] = W2half[f];
    __syncthreads();

    int wv = threadIdx.x >> 6, lane = threadIdx.x & 63;
    int n = blockIdx.x * 4 + wv;
    if (n >= N) return;
    int g = lane >> 3, cg = lane & 7;
    int beg = rowptr[n], end = rowptr[n + 1];
    unsigned cgoff = (unsigned)(cg * 4);
    const char* hb = (const char*)hq;

    GATHER_CORE(hb)

    if (g == 0) {
        float dn = dis[n];
        unsigned qs = *(const unsigned*)(hb + ((unsigned)(n * 32) + cgoff));
        f32x2 slo = __builtin_amdgcn_cvt_pk_f32_fp8(qs, false);
        f32x2 shi = __builtin_amdgcn_cvt_pk_f32_fp8(qs, true);
        float4 v;
        v.x = dn * (acc[0] + slo[0]);
        v.y = dn * (acc[1] + slo[1]);
        v.z = dn * (acc[2] + shi[0]);
        v.w = dn * (acc[3] + shi[1]);
        *(float4*)&vl[wv * 32 + cg * 4] = v;
    }

    float o;
    if (final_pass) o = (lane < OUT_CH) ? opart[(size_t)n * OUT_CH + lane] : 0.f;
    else            o = (lane < OUT_CH) ? b2[lane] : 0.f;
    const float* vrow = &vl[wv * 32];
    #pragma unroll 8
    for (int c = 0; c < 32; ++c)
        o += vrow[c] * w2l[c * OUT_CH + lane];

    if (!final_pass) {
        if (lane < OUT_CH) opart[(size_t)n * OUT_CH + lane] = o;
        return;
    }
    float mx = (lane < OUT_CH) ? o : -1e30f;
    #pragma unroll
    for (int off = 32; off > 0; off >>= 1) mx = fmaxf(mx, __shfl_xor(mx, off));
    float e = (lane < OUT_CH) ? expf(o - mx) : 0.f;
    float ssum = e;
    #pragma unroll
    for (int off = 32; off > 0; off >>= 1) ssum += __shfl_xor(ssum, off);
    if (lane < OUT_CH)
        out[(size_t)n * OUT_CH + lane] = o - mx - logf(ssum);
}

extern "C" void kernel_launch(void* const* d_in, const int* in_sizes, int n_in,
                              void* d_out, int out_size, void* d_ws, size_t ws_size,
                              hipStream_t stream) {
    const float* X  = (const float*)d_in[0];
    const int* adj  = (const int*)d_in[1];
    const float* W1 = (const float*)d_in[2];
    const float* b1 = (const float*)d_in[3];
    const float* W2 = (const float*)d_in[4];
    const float* b2 = (const float*)d_in[5];
    float* out = (float*)d_out;

    int N = in_sizes[0] / IN_CH;
    int E = in_sizes[1] / 2;
    const int* srcp = adj;
    const int* dstp = adj + E;
    int nchunk = (N + 1023) / 1024;              // 98 (<=128 required)
    int epad_max = E + 7 * N + 128;

    char* ws = (char*)d_ws;
    size_t off = 0;
    int*   cnt    = (int*)(ws + off);  off += (size_t)N * sizeof(int);
    int*   cur    = (int*)(ws + off);  off += ((size_t)N + 8) * sizeof(int);
    float* dis    = (float*)(ws + off); off += (size_t)N * sizeof(float);
    int*   rowptr = (int*)(ws + off);  off += ((size_t)N + 8) * sizeof(int);
    int*   bsum   = (int*)(ws + off);  off += 128 * sizeof(int);
    int*   esrc   = (int*)(ws + off);  off += (size_t)epad_max * sizeof(int);
    unsigned short* w1f = (unsigned short*)(ws + off); off += (size_t)IN_CH * MID_CH * sizeof(unsigned short);
    unsigned char* h1A = (unsigned char*)(ws + off); off += (size_t)(N + 4) * 32;
    unsigned char* h1B = (unsigned char*)(ws + off); off += (size_t)(N + 4) * 32;
    unsigned char* h2A = (unsigned char*)(ws + off); off += (size_t)(N + 4) * 32;
    unsigned char* h2B = (unsigned char*)(ws + off); off += (size_t)(N + 4) * 32;
    float* opart = (float*)(ws + off); off += (size_t)N * OUT_CH * sizeof(float);

    hipMemsetAsync(cnt, 0, (size_t)N * sizeof(int), stream);
    k_prepw<<<(IN_CH * MID_CH + 255) / 256, 256, 0, stream>>>(W1, w1f);
    k_count<<<(E + 255) / 256, 256, 0, stream>>>(dstp, cnt, E);
    k_scanA<<<nchunk, 1024, 0, stream>>>(cnt, rowptr, bsum, dis, N);
    k_scanB<<<1, 128, 0, stream>>>(bsum, nchunk);
    k_scanC<<<nchunk, 1024, 0, stream>>>(rowptr, cur, bsum, N);
    k_padfill<<<(epad_max + 255) / 256, 256, 0, stream>>>(esrc, N << 5, epad_max);
    // zero dummy row N of all four half-tables (padded edges point here)
    hipMemsetAsync(h1A + (size_t)N * 32, 0, 32, stream);
    hipMemsetAsync(h1B + (size_t)N * 32, 0, 32, stream);
    hipMemsetAsync(h2A + (size_t)N * 32, 0, 32, stream);
    hipMemsetAsync(h2B + (size_t)N * 32, 0, 32, stream);

    k_fill<<<1024, 256, 0, stream>>>(srcp, dstp, cur, esrc, E);
    k_gemm1<<<(N + 63) / 64, 256, 0, stream>>>(X, w1f, dis, h1A, h1B, N);

    int nb = (N + 3) / 4;
    k_agg1<<<nb, 256, 0, stream>>>(h1A, dis, rowptr, esrc, b1,      h2A, N);
    k_agg1<<<nb, 256, 0, stream>>>(h1B, dis, rowptr, esrc, b1 + 32, h2B, N);
    k_agg2<<<nb, 256, 0, stream>>>(h2A, dis, rowptr, esrc, W2,           b2, opart, out, N, 0);
    k_agg2<<<nb, 256, 0, stream>>>(h2B, dis, rowptr, esrc, W2 + 32 * OUT_CH, b2, opart, out, N, 1);
}

// Round 10
// 400.287 us; speedup vs baseline: 1.0143x; 1.0143x over previous
//
#include <hip/hip_runtime.h>
#include <hip/hip_bf16.h>
#include <math.h>

#define IN_CH 512
#define MID_CH 64
#define OUT_CH 40

typedef __attribute__((ext_vector_type(8))) short short8;
typedef __attribute__((ext_vector_type(4))) float f32x4;
typedef __attribute__((ext_vector_type(2))) float f32x2;

static __device__ __forceinline__ unsigned short f2bf(float f) {
    unsigned int u = __float_as_uint(f);
    u += 0x7fffu + ((u >> 16) & 1u);   // round-to-nearest-even on bf16 boundary
    return (unsigned short)(u >> 16);
}

// ---------------- degree count per (dst, src-half) key ----------------------------
__global__ void k_count(const int* __restrict__ src, const int* __restrict__ dst,
                        int* __restrict__ cnt2, int E, int NH) {
    int i = blockIdx.x * blockDim.x + threadIdx.x;
    if (i < E) {
        int k = dst[i] * 2 + (src[i] >= NH ? 1 : 0);
        atomicAdd(&cnt2[k], 1);
    }
}

// ---------------- CSR scan over 2N PADDED half-degrees (round up to 4) ------------
__global__ void k_scanA(const int* __restrict__ cnt2, int* __restrict__ rowptr,
                        int* __restrict__ bsum, int M) {
    __shared__ int wsum[16];
    int i = blockIdx.x * 1024 + threadIdx.x;
    int lane = threadIdx.x & 63, wv = threadIdx.x >> 6;
    int v = (i < M) ? cnt2[i] : 0;
    int x = (v + 3) & ~3;                      // padded half-degree
    #pragma unroll
    for (int off = 1; off < 64; off <<= 1) {
        int t = __shfl_up(x, off);
        if (lane >= off) x += t;
    }
    if (lane == 63) wsum[wv] = x;
    __syncthreads();
    if (wv == 0 && lane < 16) {
        int own = wsum[lane];
        int y = own;
        #pragma unroll
        for (int off = 1; off < 16; off <<= 1) {
            int t = __shfl_up(y, off);
            if (lane >= off) y += t;
        }
        wsum[lane] = y - own;
        if (lane == 15) bsum[blockIdx.x] = y;
    }
    __syncthreads();
    if (i < M) rowptr[i + 1] = x + wsum[wv];
}

// B: exclusive scan of up to 256 chunk totals (one 256-thread block)
__global__ void k_scanB(int* __restrict__ bsum, int nb) {
    __shared__ int ws[4];
    int lane = threadIdx.x & 63, wv = threadIdx.x >> 6;
    int v = (threadIdx.x < nb) ? bsum[threadIdx.x] : 0;
    int x = v;
    #pragma unroll
    for (int off = 1; off < 64; off <<= 1) {
        int t = __shfl_up(x, off);
        if (lane >= off) x += t;
    }
    if (lane == 63) ws[wv] = x;
    __syncthreads();
    if (threadIdx.x == 0) {
        int a = 0;
        #pragma unroll
        for (int j = 0; j < 4; ++j) { int t = ws[j]; ws[j] = a; a += t; }
    }
    __syncthreads();
    if (threadIdx.x < nb) bsum[threadIdx.x] = x - v + ws[wv];
}

// C: add chunk offsets; ALSO initialize cursor cur2[] = rowptr[]
__global__ void k_scanC(int* __restrict__ rowptr, int* __restrict__ cur2,
                        const int* __restrict__ bsum, int M) {
    int i = blockIdx.x * 1024 + threadIdx.x;
    if (i < M) {
        int v = rowptr[i + 1] + bsum[blockIdx.x];
        rowptr[i + 1] = v;
        cur2[i + 1] = v;
    }
    if (i == 0) { rowptr[0] = 0; cur2[0] = 0; }
}

// ---------------- padfill dummy slots + compute dis from total degree -------------
__global__ void k_padfill(int* __restrict__ esrc, int dummy_off, int total,
                          const int* __restrict__ cnt2, float* __restrict__ dis, int N) {
    int i = blockIdx.x * blockDim.x + threadIdx.x;
    if (i < total) esrc[i] = dummy_off;
    if (i < N) dis[i] = rsqrtf((float)(cnt2[2 * i] + cnt2[2 * i + 1]) + 1.0f);
}

// ---------------- fill CSR (partitioned by dst&7 for esrc write locality) ---------
__global__ void k_fill(const int* __restrict__ src, const int* __restrict__ dst,
                       int* __restrict__ cur2, int* __restrict__ esrc, int E, int NH) {
    int pb = blockIdx.x & 7;
    int ch = blockIdx.x >> 3;
    int nch = gridDim.x >> 3;
    int ech = (E + nch - 1) / nch;
    int e0 = ch * ech;
    int e1 = e0 + ech; if (e1 > E) e1 = E;
    #pragma unroll 4
    for (int e = e0 + (int)threadIdx.x; e < e1; e += blockDim.x) {
        int d = dst[e];
        if ((d & 7) == pb) {
            int s = src[e];
            int k = d * 2 + (s >= NH ? 1 : 0);
            int p = atomicAdd(&cur2[k], 1);
            esrc[p] = s << 6;           // byte offset of 64-B fp8 row
        }
    }
}

// ---------------- prep W1: fp32 [512][64] -> bf16 fragment layout -----------------
__global__ void k_prepw(const float* __restrict__ W1, unsigned short* __restrict__ w1f) {
    int f = blockIdx.x * 256 + threadIdx.x;      // 32768 total
    int k = f >> 6, c = f & 63;
    w1f[(((k >> 3) * 64) + c) * 8 + (k & 7)] = f2bf(W1[f]);
}

// ---------------- GEMM1: h1q = fp8(dis[row] * (X @ W1)), no LDS -------------------
__launch_bounds__(256, 6)
__global__ void k_gemm1(const float* __restrict__ X, const unsigned short* __restrict__ w1f,
                        const float* __restrict__ dis, unsigned char* __restrict__ h1q,
                        int N) {
    int wave = threadIdx.x >> 6, lane = threadIdx.x & 63;
    int rbase = blockIdx.x * 64 + wave * 16;
    int g = lane >> 4;
    int arow = rbase + (lane & 15);
    if (arow > N - 1) arow = N - 1;              // clamp loads; stores are guarded
    const float* xp = X + (size_t)arow * IN_CH + g * 8;
    const short8* wb = (const short8*)w1f;

    f32x4 acc[4];
    #pragma unroll
    for (int i = 0; i < 4; ++i) acc[i] = (f32x4){0.f, 0.f, 0.f, 0.f};

    float4 bx0[2], bx1[2];
    {
        const float4* p0 = (const float4*)(xp);
        const float4* p1 = (const float4*)(xp + 32);
        bx0[0] = p0[0]; bx1[0] = p0[1];
        bx0[1] = p1[0]; bx1[1] = p1[1];
    }

    #pragma unroll
    for (int ks = 0; ks < 16; ++ks) {
        float4 x0 = bx0[ks & 1], x1 = bx1[ks & 1];
        if (ks < 14) {
            const float4* p = (const float4*)(xp + (ks + 2) * 32);
            bx0[ks & 1] = p[0]; bx1[ks & 1] = p[1];
        }
        short8 a;
        a[0] = (short)f2bf(x0.x); a[1] = (short)f2bf(x0.y);
        a[2] = (short)f2bf(x0.z); a[3] = (short)f2bf(x0.w);
        a[4] = (short)f2bf(x1.x); a[5] = (short)f2bf(x1.y);
        a[6] = (short)f2bf(x1.z); a[7] = (short)f2bf(x1.w);

        int cibase = (ks * 4 + g) * 64 + (lane & 15);
        #pragma unroll
        for (int ct = 0; ct < 4; ++ct) {
            short8 b = wb[cibase + ct * 16];
            acc[ct] = __builtin_amdgcn_mfma_f32_16x16x32_bf16(a, b, acc[ct], 0, 0, 0);
        }
    }

    // D layout: col = lane&15, row = (lane>>4)*4 + reg
    int colb = lane & 15;
    int rquad = rbase + (lane >> 4) * 4;
    #pragma unroll
    for (int ct = 0; ct < 4; ++ct) {
        #pragma unroll
        for (int r = 0; r < 4; ++r) {
            int row = rquad + r;
            if (row < N) {
                float v = acc[ct][r] * dis[row];
                unsigned q = __builtin_amdgcn_cvt_pk_fp8_f32(v, v, 0, false);
                h1q[(size_t)row * 64 + ct * 16 + colb] = (unsigned char)q;
            }
        }
    }
}

// ---- fp8 gather unpack: one u32 = 4 channels ----
#define AGG_UNPACK8(Q)                                              \
    {                                                               \
        f32x2 lo_ = __builtin_amdgcn_cvt_pk_f32_fp8((Q), false);    \
        f32x2 hi_ = __builtin_amdgcn_cvt_pk_f32_fp8((Q), true);     \
        acc[0] += lo_[0]; acc[1] += lo_[1];                         \
        acc[2] += hi_[0]; acc[3] += hi_[1];                         \
    }

// ---- shared gather core: 64-B rows, 4 edge-subgroups x 16 channel-quads ----
#define GATHER_CORE(HB)                                                 \
    f32x4 acc = (f32x4){0.f, 0.f, 0.f, 0.f};                            \
    for (int cbeg = beg; cbeg < end; cbeg += 64) {                      \
        int m = end - cbeg; if (m > 64) m = 64;  /* multiple of 4 */    \
        int soff = esrc[cbeg + lane];                                   \
        int k4n = m >> 2;                                               \
        int k4 = 0;                                                     \
        for (; k4 + 4 <= k4n; k4 += 4) {                                \
            int o0 = __shfl(soff, (k4 + 0) * 4 + g);                    \
            int o1 = __shfl(soff, (k4 + 1) * 4 + g);                    \
            int o2 = __shfl(soff, (k4 + 2) * 4 + g);                    \
            int o3 = __shfl(soff, (k4 + 3) * 4 + g);                    \
            unsigned q0 = *(const unsigned*)((HB) + ((unsigned)o0 + cgoff)); \
            unsigned q1 = *(const unsigned*)((HB) + ((unsigned)o1 + cgoff)); \
            unsigned q2 = *(const unsigned*)((HB) + ((unsigned)o2 + cgoff)); \
            unsigned q3 = *(const unsigned*)((HB) + ((unsigned)o3 + cgoff)); \
            AGG_UNPACK8(q0) AGG_UNPACK8(q1) AGG_UNPACK8(q2) AGG_UNPACK8(q3) \
        }                                                               \
        for (; k4 < k4n; ++k4) {                                        \
            int o = __shfl(soff, k4 * 4 + g);                           \
            unsigned q = *(const unsigned*)((HB) + ((unsigned)o + cgoff)); \
            AGG_UNPACK8(q)                                              \
        }                                                               \
    }                                                                   \
    _Pragma("unroll")                                                   \
    for (int off = 32; off >= 16; off >>= 1) {                          \
        acc[0] += __shfl_xor(acc[0], off);                              \
        acc[1] += __shfl_xor(acc[1], off);                              \
        acc[2] += __shfl_xor(acc[2], off);                              \
        acc[3] += __shfl_xor(acc[3], off);                              \
    }

// ---------------- pass A (both layers): gather src-half-0, write fp32 partial -----
__launch_bounds__(256)
__global__ void k_aggA(const unsigned char* __restrict__ hq,
                       const int* __restrict__ rowptr, const int* __restrict__ esrc,
                       float* __restrict__ opart, int N) {
    int wv = threadIdx.x >> 6, lane = threadIdx.x & 63;
    int n = blockIdx.x * 4 + wv;
    if (n >= N) return;
    int g = lane >> 4, cg = lane & 15;
    int beg = rowptr[2 * n], end = rowptr[2 * n + 1];
    unsigned cgoff = (unsigned)(cg * 4);
    const char* hb = (const char*)hq;

    GATHER_CORE(hb)

    if (g == 0) {
        float4 v; v.x = acc[0]; v.y = acc[1]; v.z = acc[2]; v.w = acc[3];
        *(float4*)(opart + (size_t)n * 64 + cg * 4) = v;
    }
}

// ---------------- layer 1 pass B: gather src-half-1 + partial + finish + elu ------
__launch_bounds__(256)
__global__ void k_aggB1(const unsigned char* __restrict__ hq, const float* __restrict__ dis,
                        const int* __restrict__ rowptr, const int* __restrict__ esrc,
                        const float* __restrict__ b1, const float* __restrict__ opart,
                        unsigned char* __restrict__ h2q, int N) {
    int wv = threadIdx.x >> 6, lane = threadIdx.x & 63;
    int n = blockIdx.x * 4 + wv;
    if (n >= N) return;
    int g = lane >> 4, cg = lane & 15;
    int beg = rowptr[2 * n + 1], end = rowptr[2 * n + 2];
    unsigned cgoff = (unsigned)(cg * 4);
    const char* hb = (const char*)hq;

    GATHER_CORE(hb)

    if (g == 0) {
        float dn = dis[n];
        float4 pa = *(const float4*)(opart + (size_t)n * 64 + cg * 4);
        unsigned qs = *(const unsigned*)(hb + ((unsigned)(n * 64) + cgoff));
        f32x2 slo = __builtin_amdgcn_cvt_pk_f32_fp8(qs, false);
        f32x2 shi = __builtin_amdgcn_cvt_pk_f32_fp8(qs, true);
        float4 b4 = *(const float4*)(b1 + cg * 4);
        float v0 = dn * (acc[0] + pa.x + slo[0]) + b4.x;
        float v1 = dn * (acc[1] + pa.y + slo[1]) + b4.y;
        float v2 = dn * (acc[2] + pa.z + shi[0]) + b4.z;
        float v3 = dn * (acc[3] + pa.w + shi[1]) + b4.w;
        v0 = v0 > 0.f ? v0 : expm1f(v0);
        v1 = v1 > 0.f ? v1 : expm1f(v1);
        v2 = v2 > 0.f ? v2 : expm1f(v2);
        v3 = v3 > 0.f ? v3 : expm1f(v3);
        unsigned w = __builtin_amdgcn_cvt_pk_fp8_f32(dn * v0, dn * v1, 0, false);
        w = __builtin_amdgcn_cvt_pk_fp8_f32(dn * v2, dn * v3, w, true);
        *(unsigned*)(h2q + (size_t)n * 64 + cg * 4) = w;
    }
}

// ---------------- layer 2 pass B: gather half-1 + partial + GEMM2 + log_softmax ---
__launch_bounds__(256)
__global__ void k_aggB2(const unsigned char* __restrict__ hq, const float* __restrict__ dis,
                        const int* __restrict__ rowptr, const int* __restrict__ esrc,
                        const float* __restrict__ W2, const float* __restrict__ b2,
                        const float* __restrict__ opart, float* __restrict__ out, int N) {
    __shared__ float w2l[MID_CH * OUT_CH];
    __shared__ float vl[4 * MID_CH];
    for (int f = threadIdx.x; f < MID_CH * OUT_CH; f += 256) w2l[f] = W2[f];
    __syncthreads();

    int wv = threadIdx.x >> 6, lane = threadIdx.x & 63;
    int n = blockIdx.x * 4 + wv;
    if (n >= N) return;
    int g = lane >> 4, cg = lane & 15;
    int beg = rowptr[2 * n + 1], end = rowptr[2 * n + 2];
    unsigned cgoff = (unsigned)(cg * 4);
    const char* hb = (const char*)hq;

    GATHER_CORE(hb)

    if (g == 0) {
        float dn = dis[n];
        float4 pa = *(const float4*)(opart + (size_t)n * 64 + cg * 4);
        unsigned qs = *(const unsigned*)(hb + ((unsigned)(n * 64) + cgoff));
        f32x2 slo = __builtin_amdgcn_cvt_pk_f32_fp8(qs, false);
        f32x2 shi = __builtin_amdgcn_cvt_pk_f32_fp8(qs, true);
        float4 v;
        v.x = dn * (acc[0] + pa.x + slo[0]);
        v.y = dn * (acc[1] + pa.y + slo[1]);
        v.z = dn * (acc[2] + pa.z + shi[0]);
        v.w = dn * (acc[3] + pa.w + shi[1]);
        *(float4*)&vl[wv * 64 + cg * 4] = v;
    }

    float o = (lane < OUT_CH) ? b2[lane] : 0.f;
    const float* vrow = &vl[wv * 64];
    #pragma unroll 8
    for (int c = 0; c < MID_CH; ++c)
        o += vrow[c] * w2l[c * OUT_CH + lane];

    float mx = (lane < OUT_CH) ? o : -1e30f;
    #pragma unroll
    for (int off = 32; off > 0; off >>= 1) mx = fmaxf(mx, __shfl_xor(mx, off));
    float e = (lane < OUT_CH) ? expf(o - mx) : 0.f;
    float ssum = e;
    #pragma unroll
    for (int off = 32; off > 0; off >>= 1) ssum += __shfl_xor(ssum, off);
    if (lane < OUT_CH)
        out[(size_t)n * OUT_CH + lane] = o - mx - logf(ssum);
}

extern "C" void kernel_launch(void* const* d_in, const int* in_sizes, int n_in,
                              void* d_out, int out_size, void* d_ws, size_t ws_size,
                              hipStream_t stream) {
    const float* X  = (const float*)d_in[0];
    const int* adj  = (const int*)d_in[1];
    const float* W1 = (const float*)d_in[2];
    const float* b1 = (const float*)d_in[3];
    const float* W2 = (const float*)d_in[4];
    const float* b2 = (const float*)d_in[5];
    float* out = (float*)d_out;

    int N = in_sizes[0] / IN_CH;
    int E = in_sizes[1] / 2;
    const int* srcp = adj;
    const int* dstp = adj + E;
    int NH = N / 2;
    int M = 2 * N;                               // (dst, src-half) keys
    int nchunk = (M + 1023) / 1024;              // 196 (<=256 required by scanB)
    int epad_max = E + 6 * N + 128;

    char* ws = (char*)d_ws;
    size_t off = 0;
    int*   cnt2   = (int*)(ws + off);  off += (size_t)M * sizeof(int);
    int*   cur2   = (int*)(ws + off);  off += ((size_t)M + 8) * sizeof(int);
    float* dis    = (float*)(ws + off); off += (size_t)N * sizeof(float);
    int*   rowptr = (int*)(ws + off);  off += ((size_t)M + 8) * sizeof(int);
    int*   bsum   = (int*)(ws + off);  off += 256 * sizeof(int);
    int*   esrc   = (int*)(ws + off);  off += (size_t)epad_max * sizeof(int);
    unsigned short* w1f = (unsigned short*)(ws + off); off += (size_t)IN_CH * MID_CH * sizeof(unsigned short);
    unsigned char* h1q = (unsigned char*)(ws + off); off += (size_t)(N + 4) * MID_CH;
    unsigned char* h2q = (unsigned char*)(ws + off); off += (size_t)(N + 4) * MID_CH;
    float* opart = (float*)(ws + off); off += (size_t)N * MID_CH * sizeof(float);

    hipMemsetAsync(cnt2, 0, (size_t)M * sizeof(int), stream);
    k_prepw<<<(IN_CH * MID_CH + 255) / 256, 256, 0, stream>>>(W1, w1f);
    k_count<<<(E + 255) / 256, 256, 0, stream>>>(srcp, dstp, cnt2, E, NH);
    k_scanA<<<nchunk, 1024, 0, stream>>>(cnt2, rowptr, bsum, M);
    k_scanB<<<1, 256, 0, stream>>>(bsum, nchunk);
    k_scanC<<<nchunk, 1024, 0, stream>>>(rowptr, cur2, bsum, M);
    k_padfill<<<(epad_max + 255) / 256, 256, 0, stream>>>(esrc, N << 6, epad_max, cnt2, dis, N);
    // zero dummy row N of both tables (padded edges point here)
    hipMemsetAsync(h1q + (size_t)N * 64, 0, 64, stream);
    hipMemsetAsync(h2q + (size_t)N * 64, 0, 64, stream);

    k_fill<<<1024, 256, 0, stream>>>(srcp, dstp, cur2, esrc, E, NH);
    k_gemm1<<<(N + 63) / 64, 256, 0, stream>>>(X, w1f, dis, h1q, N);

    int nb = (N + 3) / 4;
    k_aggA<<<nb, 256, 0, stream>>>(h1q, rowptr, esrc, opart, N);
    k_aggB1<<<nb, 256, 0, stream>>>(h1q, dis, rowptr, esrc, b1, opart, h2q, N);
    k_aggA<<<nb, 256, 0, stream>>>(h2q, rowptr, esrc, opart, N);
    k_aggB2<<<nb, 256, 0, stream>>>(h2q, dis, rowptr, esrc, W2, b2, opart, out, N);
}

// Round 11
// 326.658 us; speedup vs baseline: 1.2430x; 1.2254x over previous
//
#include <hip/hip_runtime.h>
#include <hip/hip_bf16.h>
#include <math.h>

#define IN_CH 512
#define MID_CH 64
#define OUT_CH 40

typedef __attribute__((ext_vector_type(8))) short short8;
typedef __attribute__((ext_vector_type(4))) float f32x4;
typedef __attribute__((ext_vector_type(2))) float f32x2;

static __device__ __forceinline__ unsigned short f2bf(float f) {
    unsigned int u = __float_as_uint(f);
    u += 0x7fffu + ((u >> 16) & 1u);   // round-to-nearest-even on bf16 boundary
    return (unsigned short)(u >> 16);
}

// ---------------- fused init: cnt=0, W1 prep, esrc padfill, dummy rows ------------
// w1f layout: w1f[((k>>3)*64 + c)*8 + (k&7)] : 16B per (k-chunk, col) fragment
__global__ void k_init(const float* __restrict__ W1, unsigned short* __restrict__ w1f,
                       int* __restrict__ cnt, int* __restrict__ esrc, int dummy_off,
                       int epad, unsigned char* __restrict__ h1q,
                       unsigned char* __restrict__ h2q, int N) {
    int i = blockIdx.x * 256 + threadIdx.x;
    if (i < epad) esrc[i] = dummy_off;
    if (i < N) cnt[i] = 0;
    if (i < IN_CH * MID_CH) {
        int k = i >> 6, c = i & 63;
        w1f[(((k >> 3) * 64) + c) * 8 + (k & 7)] = f2bf(W1[i]);
    }
    if (i < 64) {
        h1q[(size_t)N * 64 + i] = 0;
        h2q[(size_t)N * 64 + i] = 0;
    }
}

// ---------------- degree count (simple; cnt is 400KB -> L2-friendly) --------------
__global__ void k_count(const int* __restrict__ dst, int* __restrict__ cnt, int E) {
    int i = blockIdx.x * blockDim.x + threadIdx.x;
    if (i < E) atomicAdd(&cnt[dst[i]], 1);
}

// ---------------- CSR scan over PADDED degrees (round up to 4); dis from real deg --
__global__ void k_scanA(const int* __restrict__ cnt, int* __restrict__ rowptr,
                        int* __restrict__ bsum, float* __restrict__ dis, int N) {
    __shared__ int wsum[16];
    int i = blockIdx.x * 1024 + threadIdx.x;
    int lane = threadIdx.x & 63, wv = threadIdx.x >> 6;
    int v = (i < N) ? cnt[i] : 0;
    if (i < N) dis[i] = rsqrtf((float)v + 1.0f);
    int x = (v + 3) & ~3;                      // padded degree (mult of 4)
    #pragma unroll
    for (int off = 1; off < 64; off <<= 1) {
        int t = __shfl_up(x, off);
        if (lane >= off) x += t;
    }
    if (lane == 63) wsum[wv] = x;
    __syncthreads();
    if (wv == 0 && lane < 16) {
        int own = wsum[lane];
        int y = own;
        #pragma unroll
        for (int off = 1; off < 16; off <<= 1) {
            int t = __shfl_up(y, off);
            if (lane >= off) y += t;
        }
        wsum[lane] = y - own;
        if (lane == 15) bsum[blockIdx.x] = y;
    }
    __syncthreads();
    if (i < N) rowptr[i + 1] = x + wsum[wv];
}

__global__ void k_scanB(int* __restrict__ bsum, int nb) {
    __shared__ int tmp[2];
    int lane = threadIdx.x & 63, wv = threadIdx.x >> 6;
    int v = (threadIdx.x < nb) ? bsum[threadIdx.x] : 0;
    int x = v;
    #pragma unroll
    for (int off = 1; off < 64; off <<= 1) {
        int t = __shfl_up(x, off);
        if (lane >= off) x += t;
    }
    if (lane == 63) tmp[wv] = x;
    __syncthreads();
    int add = (wv == 1) ? tmp[0] : 0;
    if (threadIdx.x < nb) bsum[threadIdx.x] = x - v + add;
}

// C: add chunk offsets; ALSO initialize cursor cur[] = rowptr[]
__global__ void k_scanC(int* __restrict__ rowptr, int* __restrict__ cur,
                        const int* __restrict__ bsum, int N) {
    int i = blockIdx.x * 1024 + threadIdx.x;
    if (i < N) {
        int v = rowptr[i + 1] + bsum[blockIdx.x];
        rowptr[i + 1] = v;
        cur[i + 1] = v;
    }
    if (i == 0) { rowptr[0] = 0; cur[0] = 0; }
}

// ---------------- fused: CSR fill (first FB blocks, XCD-aligned) + GEMM1 ----------
// blocks [0,FB): fill, partition pb = blockIdx&7 (all 8 XCDs); blocks >=FB: gemm.
// gemm: 256 thr = 4 waves; 64 rows x 64 cols; no LDS (w1f L1/L2-resident);
//       depth-2 prefetch ring on X; h1q = fp8(dis[row] * (X @ W1)).
__launch_bounds__(256, 6)
__global__ void k_fillgemm(const float* __restrict__ X, const unsigned short* __restrict__ w1f,
                           const float* __restrict__ dis, unsigned char* __restrict__ h1q,
                           int N, int FB,
                           const int* __restrict__ src, const int* __restrict__ dst,
                           int* __restrict__ cur, int* __restrict__ esrc, int E) {
    if ((int)blockIdx.x < FB) {
        // ---- fill path ----
        int fb = blockIdx.x;
        int pb = fb & 7;
        int ch = fb >> 3;
        int nch = FB >> 3;
        int ech = (E + nch - 1) / nch;
        int e0 = ch * ech;
        int e1 = e0 + ech; if (e1 > E) e1 = E;
        #pragma unroll 4
        for (int e = e0 + (int)threadIdx.x; e < e1; e += 256) {
            int d = dst[e];
            if ((d & 7) == pb) {
                int p = atomicAdd(&cur[d], 1);
                esrc[p] = src[e] << 6;      // byte offset of 64-B fp8 row
            }
        }
        return;
    }

    // ---- gemm path ----
    int wave = threadIdx.x >> 6, lane = threadIdx.x & 63;
    int gb = blockIdx.x - FB;
    int rbase = gb * 64 + wave * 16;
    int g = lane >> 4;
    int arow = rbase + (lane & 15);
    if (arow > N - 1) arow = N - 1;              // clamp loads; stores are guarded
    const float* xp = X + (size_t)arow * IN_CH + g * 8;
    const short8* wb = (const short8*)w1f;

    f32x4 acc[4];
    #pragma unroll
    for (int i = 0; i < 4; ++i) acc[i] = (f32x4){0.f, 0.f, 0.f, 0.f};

    float4 bx0[2], bx1[2];
    {
        const float4* p0 = (const float4*)(xp);
        const float4* p1 = (const float4*)(xp + 32);
        bx0[0] = p0[0]; bx1[0] = p0[1];
        bx0[1] = p1[0]; bx1[1] = p1[1];
    }

    #pragma unroll
    for (int ks = 0; ks < 16; ++ks) {
        float4 x0 = bx0[ks & 1], x1 = bx1[ks & 1];
        if (ks < 14) {
            const float4* p = (const float4*)(xp + (ks + 2) * 32);
            bx0[ks & 1] = p[0]; bx1[ks & 1] = p[1];
        }
        short8 a;
        a[0] = (short)f2bf(x0.x); a[1] = (short)f2bf(x0.y);
        a[2] = (short)f2bf(x0.z); a[3] = (short)f2bf(x0.w);
        a[4] = (short)f2bf(x1.x); a[5] = (short)f2bf(x1.y);
        a[6] = (short)f2bf(x1.z); a[7] = (short)f2bf(x1.w);

        int cibase = (ks * 4 + g) * 64 + (lane & 15);
        #pragma unroll
        for (int ct = 0; ct < 4; ++ct) {
            short8 b = wb[cibase + ct * 16];
            acc[ct] = __builtin_amdgcn_mfma_f32_16x16x32_bf16(a, b, acc[ct], 0, 0, 0);
        }
    }

    // D layout: col = lane&15, row = (lane>>4)*4 + reg
    int colb = lane & 15;
    int rquad = rbase + (lane >> 4) * 4;
    #pragma unroll
    for (int ct = 0; ct < 4; ++ct) {
        #pragma unroll
        for (int r = 0; r < 4; ++r) {
            int row = rquad + r;
            if (row < N) {
                float v = acc[ct][r] * dis[row];
                unsigned q = __builtin_amdgcn_cvt_pk_fp8_f32(v, v, 0, false);
                h1q[(size_t)row * 64 + ct * 16 + colb] = (unsigned char)q;
            }
        }
    }
}

// ---- fp8 gather unpack: one u32 = 4 channels ----
#define AGG_UNPACK8(Q)                                              \
    {                                                               \
        f32x2 lo_ = __builtin_amdgcn_cvt_pk_f32_fp8((Q), false);    \
        f32x2 hi_ = __builtin_amdgcn_cvt_pk_f32_fp8((Q), true);     \
        acc[0] += lo_[0]; acc[1] += lo_[1];                         \
        acc[2] += hi_[0]; acc[3] += hi_[1];                         \
    }

// ---- shared gather core: 64-B rows, 4 edge-subgroups x 16 channel-quads ----
#define GATHER_CORE(HB)                                                 \
    f32x4 acc = (f32x4){0.f, 0.f, 0.f, 0.f};                            \
    for (int cbeg = beg; cbeg < end; cbeg += 64) {                      \
        int m = end - cbeg; if (m > 64) m = 64;  /* multiple of 4 */    \
        int soff = esrc[cbeg + lane];                                   \
        int k4n = m >> 2;                                               \
        int k4 = 0;                                                     \
        for (; k4 + 4 <= k4n; k4 += 4) {                                \
            int o0 = __shfl(soff, (k4 + 0) * 4 + g);                    \
            int o1 = __shfl(soff, (k4 + 1) * 4 + g);                    \
            int o2 = __shfl(soff, (k4 + 2) * 4 + g);                    \
            int o3 = __shfl(soff, (k4 + 3) * 4 + g);                    \
            unsigned q0 = *(const unsigned*)((HB) + ((unsigned)o0 + cgoff)); \
            unsigned q1 = *(const unsigned*)((HB) + ((unsigned)o1 + cgoff)); \
            unsigned q2 = *(const unsigned*)((HB) + ((unsigned)o2 + cgoff)); \
            unsigned q3 = *(const unsigned*)((HB) + ((unsigned)o3 + cgoff)); \
            AGG_UNPACK8(q0) AGG_UNPACK8(q1) AGG_UNPACK8(q2) AGG_UNPACK8(q3) \
        }                                                               \
        for (; k4 < k4n; ++k4) {                                        \
            int o = __shfl(soff, k4 * 4 + g);                           \
            unsigned q = *(const unsigned*)((HB) + ((unsigned)o + cgoff)); \
            AGG_UNPACK8(q)                                              \
        }                                                               \
    }                                                                   \
    _Pragma("unroll")                                                   \
    for (int off = 32; off >= 16; off >>= 1) {                          \
        acc[0] += __shfl_xor(acc[0], off);                              \
        acc[1] += __shfl_xor(acc[1], off);                              \
        acc[2] += __shfl_xor(acc[2], off);                              \
        acc[3] += __shfl_xor(acc[3], off);                              \
    }

// ---------------- layer 1: gather + finish + elu (one wave per node) --------------
__launch_bounds__(256)
__global__ void k_agg1(const unsigned char* __restrict__ hq, const float* __restrict__ dis,
                       const int* __restrict__ rowptr, const int* __restrict__ esrc,
                       const float* __restrict__ b1, unsigned char* __restrict__ h2q,
                       int N) {
    int wv = threadIdx.x >> 6, lane = threadIdx.x & 63;
    int n = blockIdx.x * 4 + wv;
    if (n >= N) return;
    int g = lane >> 4, cg = lane & 15;
    int beg = rowptr[n], end = rowptr[n + 1];
    unsigned cgoff = (unsigned)(cg * 4);
    const char* hb = (const char*)hq;

    GATHER_CORE(hb)

    if (g == 0) {
        float dn = dis[n];
        unsigned qs = *(const unsigned*)(hb + ((unsigned)(n * 64) + cgoff));
        f32x2 slo = __builtin_amdgcn_cvt_pk_f32_fp8(qs, false);
        f32x2 shi = __builtin_amdgcn_cvt_pk_f32_fp8(qs, true);
        float4 b4 = *(const float4*)(b1 + cg * 4);
        float v0 = dn * (acc[0] + slo[0]) + b4.x;
        float v1 = dn * (acc[1] + slo[1]) + b4.y;
        float v2 = dn * (acc[2] + shi[0]) + b4.z;
        float v3 = dn * (acc[3] + shi[1]) + b4.w;
        v0 = v0 > 0.f ? v0 : expm1f(v0);
        v1 = v1 > 0.f ? v1 : expm1f(v1);
        v2 = v2 > 0.f ? v2 : expm1f(v2);
        v3 = v3 > 0.f ? v3 : expm1f(v3);
        unsigned w = __builtin_amdgcn_cvt_pk_fp8_f32(dn * v0, dn * v1, 0, false);
        w = __builtin_amdgcn_cvt_pk_fp8_f32(dn * v2, dn * v3, w, true);
        *(unsigned*)(h2q + (size_t)n * 64 + cg * 4) = w;
    }
}

// ---------------- layer 2: gather + GEMM2 + log_softmax ---------------------------
__launch_bounds__(256)
__global__ void k_agg2(const unsigned char* __restrict__ hq, const float* __restrict__ dis,
                       const int* __restrict__ rowptr, const int* __restrict__ esrc,
                       const float* __restrict__ W2, const float* __restrict__ b2,
                       float* __restrict__ out, int N) {
    __shared__ float w2l[MID_CH * OUT_CH];
    __shared__ float vl[4 * MID_CH];
    for (int f = threadIdx.x; f < MID_CH * OUT_CH; f += 256) w2l[f] = W2[f];
    __syncthreads();

    int wv = threadIdx.x >> 6, lane = threadIdx.x & 63;
    int n = blockIdx.x * 4 + wv;
    if (n >= N) return;
    int g = lane >> 4, cg = lane & 15;
    int beg = rowptr[n], end = rowptr[n + 1];
    unsigned cgoff = (unsigned)(cg * 4);
    const char* hb = (const char*)hq;

    GATHER_CORE(hb)

    if (g == 0) {
        float dn = dis[n];
        unsigned qs = *(const unsigned*)(hb + ((unsigned)(n * 64) + cgoff));
        f32x2 slo = __builtin_amdgcn_cvt_pk_f32_fp8(qs, false);
        f32x2 shi = __builtin_amdgcn_cvt_pk_f32_fp8(qs, true);
        float4 v;
        v.x = dn * (acc[0] + slo[0]);
        v.y = dn * (acc[1] + slo[1]);
        v.z = dn * (acc[2] + shi[0]);
        v.w = dn * (acc[3] + shi[1]);
        *(float4*)&vl[wv * 64 + cg * 4] = v;
    }

    float o = (lane < OUT_CH) ? b2[lane] : 0.f;
    const float* vrow = &vl[wv * 64];
    #pragma unroll 8
    for (int c = 0; c < MID_CH; ++c)
        o += vrow[c] * w2l[c * OUT_CH + lane];

    float mx = (lane < OUT_CH) ? o : -1e30f;
    #pragma unroll
    for (int off = 32; off > 0; off >>= 1) mx = fmaxf(mx, __shfl_xor(mx, off));
    float e = (lane < OUT_CH) ? expf(o - mx) : 0.f;
    float ssum = e;
    #pragma unroll
    for (int off = 32; off > 0; off >>= 1) ssum += __shfl_xor(ssum, off);
    if (lane < OUT_CH)
        out[(size_t)n * OUT_CH + lane] = o - mx - logf(ssum);
}

extern "C" void kernel_launch(void* const* d_in, const int* in_sizes, int n_in,
                              void* d_out, int out_size, void* d_ws, size_t ws_size,
                              hipStream_t stream) {
    const float* X  = (const float*)d_in[0];
    const int* adj  = (const int*)d_in[1];
    const float* W1 = (const float*)d_in[2];
    const float* b1 = (const float*)d_in[3];
    const float* W2 = (const float*)d_in[4];
    const float* b2 = (const float*)d_in[5];
    float* out = (float*)d_out;

    int N = in_sizes[0] / IN_CH;
    int E = in_sizes[1] / 2;
    const int* srcp = adj;
    const int* dstp = adj + E;
    int nchunk = (N + 1023) / 1024;              // 98 (<=128 required by scanB)
    int epad_max = E + 3 * N + 128;
    int FB = 1024;                               // fill blocks (mult of 8)
    int GB = (N + 63) / 64;                      // gemm blocks

    char* ws = (char*)d_ws;
    size_t off = 0;
    int*   cnt    = (int*)(ws + off);  off += (size_t)N * sizeof(int);
    int*   cur    = (int*)(ws + off);  off += ((size_t)N + 8) * sizeof(int);
    float* dis    = (float*)(ws + off); off += (size_t)N * sizeof(float);
    int*   rowptr = (int*)(ws + off);  off += ((size_t)N + 8) * sizeof(int);
    int*   bsum   = (int*)(ws + off);  off += 128 * sizeof(int);
    int*   esrc   = (int*)(ws + off);  off += (size_t)epad_max * sizeof(int);
    unsigned short* w1f = (unsigned short*)(ws + off); off += (size_t)IN_CH * MID_CH * sizeof(unsigned short);
    unsigned char* h1q = (unsigned char*)(ws + off); off += (size_t)(N + 4) * MID_CH;
    unsigned char* h2q = (unsigned char*)(ws + off); off += (size_t)(N + 4) * MID_CH;

    k_init<<<(epad_max + 255) / 256, 256, 0, stream>>>(W1, w1f, cnt, esrc, N << 6,
                                                       epad_max, h1q, h2q, N);
    k_count<<<(E + 255) / 256, 256, 0, stream>>>(dstp, cnt, E);
    k_scanA<<<nchunk, 1024, 0, stream>>>(cnt, rowptr, bsum, dis, N);
    k_scanB<<<1, 128, 0, stream>>>(bsum, nchunk);
    k_scanC<<<nchunk, 1024, 0, stream>>>(rowptr, cur, bsum, N);

    k_fillgemm<<<FB + GB, 256, 0, stream>>>(X, w1f, dis, h1q, N, FB,
                                            srcp, dstp, cur, esrc, E);

    int nb = (N + 3) / 4;
    k_agg1<<<nb, 256, 0, stream>>>(h1q, dis, rowptr, esrc, b1, h2q, N);
    k_agg2<<<nb, 256, 0, stream>>>(h2q, dis, rowptr, esrc, W2, b2, out, N);
}

// Round 12
// 326.256 us; speedup vs baseline: 1.2445x; 1.0012x over previous
//
#include <hip/hip_runtime.h>
#include <hip/hip_bf16.h>
#include <math.h>

#define IN_CH 512
#define MID_CH 64
#define OUT_CH 40

typedef __attribute__((ext_vector_type(8))) short short8;
typedef __attribute__((ext_vector_type(4))) float f32x4;
typedef __attribute__((ext_vector_type(2))) float f32x2;

static __device__ __forceinline__ unsigned short f2bf(float f) {
    unsigned int u = __float_as_uint(f);
    u += 0x7fffu + ((u >> 16) & 1u);   // round-to-nearest-even on bf16 boundary
    return (unsigned short)(u >> 16);
}

// ---------------- fused init: cnt=0, W1 prep, esrc padfill, dummy rows ------------
__global__ void k_init(const float* __restrict__ W1, unsigned short* __restrict__ w1f,
                       int* __restrict__ cnt, int* __restrict__ esrc, int dummy_off,
                       int epad, unsigned char* __restrict__ h1q,
                       unsigned char* __restrict__ h2q, int N) {
    int i = blockIdx.x * 256 + threadIdx.x;
    if (i < epad) esrc[i] = dummy_off;
    if (i < N) cnt[i] = 0;
    if (i < IN_CH * MID_CH) {
        int k = i >> 6, c = i & 63;
        w1f[(((k >> 3) * 64) + c) * 8 + (k & 7)] = f2bf(W1[i]);
    }
    if (i < 64) {
        h1q[(size_t)N * 64 + i] = 0;
        h2q[(size_t)N * 64 + i] = 0;
    }
}

// ---------------- degree count (simple; cnt is 400KB -> L2-friendly) --------------
__global__ void k_count(const int* __restrict__ dst, int* __restrict__ cnt, int E) {
    int i = blockIdx.x * blockDim.x + threadIdx.x;
    if (i < E) atomicAdd(&cnt[dst[i]], 1);
}

// ---------------- CSR scan over PADDED degrees (round up to 4); dis from real deg --
__global__ void k_scanA(const int* __restrict__ cnt, int* __restrict__ rowptr,
                        int* __restrict__ bsum, float* __restrict__ dis, int N) {
    __shared__ int wsum[16];
    int i = blockIdx.x * 1024 + threadIdx.x;
    int lane = threadIdx.x & 63, wv = threadIdx.x >> 6;
    int v = (i < N) ? cnt[i] : 0;
    if (i < N) dis[i] = rsqrtf((float)v + 1.0f);
    int x = (v + 3) & ~3;                      // padded degree (mult of 4)
    #pragma unroll
    for (int off = 1; off < 64; off <<= 1) {
        int t = __shfl_up(x, off);
        if (lane >= off) x += t;
    }
    if (lane == 63) wsum[wv] = x;
    __syncthreads();
    if (wv == 0 && lane < 16) {
        int own = wsum[lane];
        int y = own;
        #pragma unroll
        for (int off = 1; off < 16; off <<= 1) {
            int t = __shfl_up(y, off);
            if (lane >= off) y += t;
        }
        wsum[lane] = y - own;
        if (lane == 15) bsum[blockIdx.x] = y;
    }
    __syncthreads();
    if (i < N) rowptr[i + 1] = x + wsum[wv];
}

__global__ void k_scanB(int* __restrict__ bsum, int nb) {
    __shared__ int tmp[2];
    int lane = threadIdx.x & 63, wv = threadIdx.x >> 6;
    int v = (threadIdx.x < nb) ? bsum[threadIdx.x] : 0;
    int x = v;
    #pragma unroll
    for (int off = 1; off < 64; off <<= 1) {
        int t = __shfl_up(x, off);
        if (lane >= off) x += t;
    }
    if (lane == 63) tmp[wv] = x;
    __syncthreads();
    int add = (wv == 1) ? tmp[0] : 0;
    if (threadIdx.x < nb) bsum[threadIdx.x] = x - v + add;
}

// C: add chunk offsets; ALSO initialize cursor cur[] = rowptr[]
__global__ void k_scanC(int* __restrict__ rowptr, int* __restrict__ cur,
                        const int* __restrict__ bsum, int N) {
    int i = blockIdx.x * 1024 + threadIdx.x;
    if (i < N) {
        int v = rowptr[i + 1] + bsum[blockIdx.x];
        rowptr[i + 1] = v;
        cur[i + 1] = v;
    }
    if (i == 0) { rowptr[0] = 0; cur[0] = 0; }
}

// ---------------- fused: CSR fill (contiguous dst-range partitions) + GEMM1 -------
// blocks [0,FB): fill, partition pb = blockIdx&7 -> dst range [pb*N/8,(pb+1)*N/8);
// contiguous esrc region per partition => one XCD writer per 64B line.
// blocks >=FB: gemm, 256 thr = 4 waves; 64 rows x 64 cols; no LDS.
__launch_bounds__(256, 6)
__global__ void k_fillgemm(const float* __restrict__ X, const unsigned short* __restrict__ w1f,
                           const float* __restrict__ dis, unsigned char* __restrict__ h1q,
                           int N, int FB,
                           const int* __restrict__ src, const int* __restrict__ dst,
                           int* __restrict__ cur, int* __restrict__ esrc, int E) {
    if ((int)blockIdx.x < FB) {
        // ---- fill path ----
        int fb = blockIdx.x;
        int pb = fb & 7;
        int ch = fb >> 3;
        int nch = FB >> 3;
        int r0 = (int)(((long long)pb * N) >> 3);
        int r1 = (int)(((long long)(pb + 1) * N) >> 3);
        int ech = (E + nch - 1) / nch;
        int e0 = ch * ech;
        int e1 = e0 + ech; if (e1 > E) e1 = E;
        #pragma unroll 4
        for (int e = e0 + (int)threadIdx.x; e < e1; e += 256) {
            int d = dst[e];
            if (d >= r0 && d < r1) {
                int p = atomicAdd(&cur[d], 1);
                esrc[p] = src[e] << 6;      // byte offset of 64-B fp8 row
            }
        }
        return;
    }

    // ---- gemm path ----
    int wave = threadIdx.x >> 6, lane = threadIdx.x & 63;
    int gb = blockIdx.x - FB;
    int rbase = gb * 64 + wave * 16;
    int g = lane >> 4;
    int arow = rbase + (lane & 15);
    if (arow > N - 1) arow = N - 1;              // clamp loads; stores are guarded
    const float* xp = X + (size_t)arow * IN_CH + g * 8;
    const short8* wb = (const short8*)w1f;

    f32x4 acc[4];
    #pragma unroll
    for (int i = 0; i < 4; ++i) acc[i] = (f32x4){0.f, 0.f, 0.f, 0.f};

    float4 bx0[2], bx1[2];
    {
        const float4* p0 = (const float4*)(xp);
        const float4* p1 = (const float4*)(xp + 32);
        bx0[0] = p0[0]; bx1[0] = p0[1];
        bx0[1] = p1[0]; bx1[1] = p1[1];
    }

    #pragma unroll
    for (int ks = 0; ks < 16; ++ks) {
        float4 x0 = bx0[ks & 1], x1 = bx1[ks & 1];
        if (ks < 14) {
            const float4* p = (const float4*)(xp + (ks + 2) * 32);
            bx0[ks & 1] = p[0]; bx1[ks & 1] = p[1];
        }
        short8 a;
        a[0] = (short)f2bf(x0.x); a[1] = (short)f2bf(x0.y);
        a[2] = (short)f2bf(x0.z); a[3] = (short)f2bf(x0.w);
        a[4] = (short)f2bf(x1.x); a[5] = (short)f2bf(x1.y);
        a[6] = (short)f2bf(x1.z); a[7] = (short)f2bf(x1.w);

        int cibase = (ks * 4 + g) * 64 + (lane & 15);
        #pragma unroll
        for (int ct = 0; ct < 4; ++ct) {
            short8 b = wb[cibase + ct * 16];
            acc[ct] = __builtin_amdgcn_mfma_f32_16x16x32_bf16(a, b, acc[ct], 0, 0, 0);
        }
    }

    // D layout: col = lane&15, row = (lane>>4)*4 + reg
    int colb = lane & 15;
    int rquad = rbase + (lane >> 4) * 4;
    #pragma unroll
    for (int ct = 0; ct < 4; ++ct) {
        #pragma unroll
        for (int r = 0; r < 4; ++r) {
            int row = rquad + r;
            if (row < N) {
                float v = acc[ct][r] * dis[row];
                unsigned q = __builtin_amdgcn_cvt_pk_fp8_f32(v, v, 0, false);
                h1q[(size_t)row * 64 + ct * 16 + colb] = (unsigned char)q;
            }
        }
    }
}

// ---- fp8 gather unpack: one u32 = 4 channels ----
#define AGG_UNPACK8(Q)                                              \
    {                                                               \
        f32x2 lo_ = __builtin_amdgcn_cvt_pk_f32_fp8((Q), false);    \
        f32x2 hi_ = __builtin_amdgcn_cvt_pk_f32_fp8((Q), true);     \
        acc[0] += lo_[0]; acc[1] += lo_[1];                         \
        acc[2] += hi_[0]; acc[3] += hi_[1];                         \
    }

// ---- shared gather core: 64-B rows, 4 edge-subgroups x 16 channel-quads ----
#define GATHER_CORE(HB)                                                 \
    f32x4 acc = (f32x4){0.f, 0.f, 0.f, 0.f};                            \
    for (int cbeg = beg; cbeg < end; cbeg += 64) {                      \
        int m = end - cbeg; if (m > 64) m = 64;  /* multiple of 4 */    \
        int soff = esrc[cbeg + lane];                                   \
        int k4n = m >> 2;                                               \
        int k4 = 0;                                                     \
        for (; k4 + 4 <= k4n; k4 += 4) {                                \
            int o0 = __shfl(soff, (k4 + 0) * 4 + g);                    \
            int o1 = __shfl(soff, (k4 + 1) * 4 + g);                    \
            int o2 = __shfl(soff, (k4 + 2) * 4 + g);                    \
            int o3 = __shfl(soff, (k4 + 3) * 4 + g);                    \
            unsigned q0 = *(const unsigned*)((HB) + ((unsigned)o0 + cgoff)); \
            unsigned q1 = *(const unsigned*)((HB) + ((unsigned)o1 + cgoff)); \
            unsigned q2 = *(const unsigned*)((HB) + ((unsigned)o2 + cgoff)); \
            unsigned q3 = *(const unsigned*)((HB) + ((unsigned)o3 + cgoff)); \
            AGG_UNPACK8(q0) AGG_UNPACK8(q1) AGG_UNPACK8(q2) AGG_UNPACK8(q3) \
        }                                                               \
        for (; k4 < k4n; ++k4) {                                        \
            int o = __shfl(soff, k4 * 4 + g);                           \
            unsigned q = *(const unsigned*)((HB) + ((unsigned)o + cgoff)); \
            AGG_UNPACK8(q)                                              \
        }                                                               \
    }                                                                   \
    _Pragma("unroll")                                                   \
    for (int off = 32; off >= 16; off >>= 1) {                          \
        acc[0] += __shfl_xor(acc[0], off);                              \
        acc[1] += __shfl_xor(acc[1], off);                              \
        acc[2] += __shfl_xor(acc[2], off);                              \
        acc[3] += __shfl_xor(acc[3], off);                              \
    }

// ---------------- layer 1: gather + finish + elu (one wave per node) --------------
__launch_bounds__(256)
__global__ void k_agg1(const unsigned char* __restrict__ hq, const float* __restrict__ dis,
                       const int* __restrict__ rowptr, const int* __restrict__ esrc,
                       const float* __restrict__ b1, unsigned char* __restrict__ h2q,
                       int N) {
    int wv = threadIdx.x >> 6, lane = threadIdx.x & 63;
    int n = blockIdx.x * 4 + wv;
    if (n >= N) return;
    int g = lane >> 4, cg = lane & 15;
    int beg = rowptr[n], end = rowptr[n + 1];
    unsigned cgoff = (unsigned)(cg * 4);
    const char* hb = (const char*)hq;

    GATHER_CORE(hb)

    if (g == 0) {
        float dn = dis[n];
        unsigned qs = *(const unsigned*)(hb + ((unsigned)(n * 64) + cgoff));
        f32x2 slo = __builtin_amdgcn_cvt_pk_f32_fp8(qs, false);
        f32x2 shi = __builtin_amdgcn_cvt_pk_f32_fp8(qs, true);
        float4 b4 = *(const float4*)(b1 + cg * 4);
        float v0 = dn * (acc[0] + slo[0]) + b4.x;
        float v1 = dn * (acc[1] + slo[1]) + b4.y;
        float v2 = dn * (acc[2] + shi[0]) + b4.z;
        float v3 = dn * (acc[3] + shi[1]) + b4.w;
        v0 = v0 > 0.f ? v0 : expm1f(v0);
        v1 = v1 > 0.f ? v1 : expm1f(v1);
        v2 = v2 > 0.f ? v2 : expm1f(v2);
        v3 = v3 > 0.f ? v3 : expm1f(v3);
        unsigned w = __builtin_amdgcn_cvt_pk_fp8_f32(dn * v0, dn * v1, 0, false);
        w = __builtin_amdgcn_cvt_pk_fp8_f32(dn * v2, dn * v3, w, true);
        *(unsigned*)(h2q + (size_t)n * 64 + cg * 4) = w;
    }
}

// ---------------- layer 2: gather + GEMM2 + log_softmax ---------------------------
__launch_bounds__(256)
__global__ void k_agg2(const unsigned char* __restrict__ hq, const float* __restrict__ dis,
                       const int* __restrict__ rowptr, const int* __restrict__ esrc,
                       const float* __restrict__ W2, const float* __restrict__ b2,
                       float* __restrict__ out, int N) {
    __shared__ float w2l[MID_CH * OUT_CH];
    __shared__ float vl[4 * MID_CH];
    for (int f = threadIdx.x; f < MID_CH * OUT_CH; f += 256) w2l[f] = W2[f];
    __syncthreads();

    int wv = threadIdx.x >> 6, lane = threadIdx.x & 63;
    int n = blockIdx.x * 4 + wv;
    if (n >= N) return;
    int g = lane >> 4, cg = lane & 15;
    int beg = rowptr[n], end = rowptr[n + 1];
    unsigned cgoff = (unsigned)(cg * 4);
    const char* hb = (const char*)hq;

    GATHER_CORE(hb)

    if (g == 0) {
        float dn = dis[n];
        unsigned qs = *(const unsigned*)(hb + ((unsigned)(n * 64) + cgoff));
        f32x2 slo = __builtin_amdgcn_cvt_pk_f32_fp8(qs, false);
        f32x2 shi = __builtin_amdgcn_cvt_pk_f32_fp8(qs, true);
        float4 v;
        v.x = dn * (acc[0] + slo[0]);
        v.y = dn * (acc[1] + slo[1]);
        v.z = dn * (acc[2] + shi[0]);
        v.w = dn * (acc[3] + shi[1]);
        *(float4*)&vl[wv * 64 + cg * 4] = v;
    }

    float o = (lane < OUT_CH) ? b2[lane] : 0.f;
    const float* vrow = &vl[wv * 64];
    #pragma unroll 8
    for (int c = 0; c < MID_CH; ++c)
        o += vrow[c] * w2l[c * OUT_CH + lane];

    float mx = (lane < OUT_CH) ? o : -1e30f;
    #pragma unroll
    for (int off = 32; off > 0; off >>= 1) mx = fmaxf(mx, __shfl_xor(mx, off));
    float e = (lane < OUT_CH) ? expf(o - mx) : 0.f;
    float ssum = e;
    #pragma unroll
    for (int off = 32; off > 0; off >>= 1) ssum += __shfl_xor(ssum, off);
    if (lane < OUT_CH)
        out[(size_t)n * OUT_CH + lane] = o - mx - logf(ssum);
}

extern "C" void kernel_launch(void* const* d_in, const int* in_sizes, int n_in,
                              void* d_out, int out_size, void* d_ws, size_t ws_size,
                              hipStream_t stream) {
    const float* X  = (const float*)d_in[0];
    const int* adj  = (const int*)d_in[1];
    const float* W1 = (const float*)d_in[2];
    const float* b1 = (const float*)d_in[3];
    const float* W2 = (const float*)d_in[4];
    const float* b2 = (const float*)d_in[5];
    float* out = (float*)d_out;

    int N = in_sizes[0] / IN_CH;
    int E = in_sizes[1] / 2;
    const int* srcp = adj;
    const int* dstp = adj + E;
    int nchunk = (N + 1023) / 1024;              // 98 (<=128 required by scanB)
    int epad_max = E + 3 * N + 128;
    int FB = 1024;                               // fill blocks (mult of 8)
    int GB = (N + 63) / 64;                      // gemm blocks

    char* ws = (char*)d_ws;
    size_t off = 0;
    int*   cnt    = (int*)(ws + off);  off += (size_t)N * sizeof(int);
    int*   cur    = (int*)(ws + off);  off += ((size_t)N + 8) * sizeof(int);
    float* dis    = (float*)(ws + off); off += (size_t)N * sizeof(float);
    int*   rowptr = (int*)(ws + off);  off += ((size_t)N + 8) * sizeof(int);
    int*   bsum   = (int*)(ws + off);  off += 128 * sizeof(int);
    int*   esrc   = (int*)(ws + off);  off += (size_t)epad_max * sizeof(int);
    unsigned short* w1f = (unsigned short*)(ws + off); off += (size_t)IN_CH * MID_CH * sizeof(unsigned short);
    unsigned char* h1q = (unsigned char*)(ws + off); off += (size_t)(N + 4) * MID_CH;
    unsigned char* h2q = (unsigned char*)(ws + off); off += (size_t)(N + 4) * MID_CH;

    k_init<<<(epad_max + 255) / 256, 256, 0, stream>>>(W1, w1f, cnt, esrc, N << 6,
                                                       epad_max, h1q, h2q, N);
    k_count<<<(E + 255) / 256, 256, 0, stream>>>(dstp, cnt, E);
    k_scanA<<<nchunk, 1024, 0, stream>>>(cnt, rowptr, bsum, dis, N);
    k_scanB<<<1, 128, 0, stream>>>(bsum, nchunk);
    k_scanC<<<nchunk, 1024, 0, stream>>>(rowptr, cur, bsum, N);

    k_fillgemm<<<FB + GB, 256, 0, stream>>>(X, w1f, dis, h1q, N, FB,
                                            srcp, dstp, cur, esrc, E);

    int nb = (N + 3) / 4;
    k_agg1<<<nb, 256, 0, stream>>>(h1q, dis, rowptr, esrc, b1, h2q, N);
    k_agg2<<<nb, 256, 0, stream>>>(h2q, dis, rowptr, esrc, W2, b2, out, N);
}